// Round 1
// baseline (671.279 us; speedup 1.0000x reference)
//
#include <hip/hip_runtime.h>

// Attention block: x_s = softmax(qk^T)[:4096,4096:] @ query @ Wps^T
//                  x_q = softmax(qk^T)[4096:,:4096] @ s     @ Wpq^T
// All heavy GEMMs in bf16 MFMA (16x16x32), fp32 accumulate.
// Softmax without max-subtraction (scores bounded ~|14|): exp fused into
// score-GEMM epilogue, row-sums via shfl-reduce + atomics, normalization
// deferred to the PV-GEMM epilogue.

typedef unsigned short u16;
typedef __bf16 bf16x8 __attribute__((ext_vector_type(8)));
typedef float f32x4 __attribute__((ext_vector_type(4)));
typedef unsigned short u16x8 __attribute__((ext_vector_type(8)));

#define DEVI static __device__ __forceinline__

DEVI u16 f2b(float f) {  // fp32 -> bf16 round-to-nearest-even
  unsigned int u = __float_as_uint(f);
  u += 0x7fffu + ((u >> 16) & 1u);
  return (u16)(u >> 16);
}

// ---------------- prep kernels ----------------

// cB (8192x1024 bf16): rows 0..4095 = bf16(s+TG), rows 4096.. = bf16(query)
__global__ void prep_c(const float* __restrict__ query, const float* __restrict__ s,
                       const float* __restrict__ tg, u16* __restrict__ cB) {
  int base = (blockIdx.x * 256 + threadIdx.x) << 3;  // 8 elements/thread
  int row = base >> 10;
  u16x8 o;
  if (row < 4096) {
    float4 a0 = *(const float4*)(s + base);
    float4 a1 = *(const float4*)(s + base + 4);
    float4 b0 = *(const float4*)(tg + base);
    float4 b1 = *(const float4*)(tg + base + 4);
    o[0] = f2b(a0.x + b0.x); o[1] = f2b(a0.y + b0.y);
    o[2] = f2b(a0.z + b0.z); o[3] = f2b(a0.w + b0.w);
    o[4] = f2b(a1.x + b1.x); o[5] = f2b(a1.y + b1.y);
    o[6] = f2b(a1.z + b1.z); o[7] = f2b(a1.w + b1.w);
  } else {
    int qb = base - 4096 * 1024;
    float4 a0 = *(const float4*)(query + qb);
    float4 a1 = *(const float4*)(query + qb + 4);
    o[0] = f2b(a0.x); o[1] = f2b(a0.y); o[2] = f2b(a0.z); o[3] = f2b(a0.w);
    o[4] = f2b(a1.x); o[5] = f2b(a1.y); o[6] = f2b(a1.z); o[7] = f2b(a1.w);
  }
  *(u16x8*)(cB + base) = o;
}

__global__ void conv_bf16(const float* __restrict__ in, u16* __restrict__ out) {
  int base = (blockIdx.x * 256 + threadIdx.x) << 3;
  float4 a0 = *(const float4*)(in + base);
  float4 a1 = *(const float4*)(in + base + 4);
  u16x8 o;
  o[0] = f2b(a0.x); o[1] = f2b(a0.y); o[2] = f2b(a0.z); o[3] = f2b(a0.w);
  o[4] = f2b(a1.x); o[5] = f2b(a1.y); o[6] = f2b(a1.z); o[7] = f2b(a1.w);
  *(u16x8*)(out + base) = o;
}

// out (C x R bf16) = transpose of in (R x C fp32)
__global__ void transpose_bf16(const float* __restrict__ in, u16* __restrict__ out,
                               int R, int C) {
  __shared__ float tile[32][33];
  int c0 = blockIdx.x * 32, r0 = blockIdx.y * 32;
  int tx = threadIdx.x, ty = threadIdx.y;  // blockDim (32,8)
#pragma unroll
  for (int i = 0; i < 4; ++i)
    tile[ty + i * 8][tx] = in[(size_t)(r0 + ty + i * 8) * C + c0 + tx];
  __syncthreads();
#pragma unroll
  for (int i = 0; i < 4; ++i)
    out[(size_t)(c0 + ty + i * 8) * R + r0 + tx] = f2b(tile[tx][ty + i * 8]);
}

// ---------------- GEMM: C[M,N] = A[M,K] @ B[N,K]^T (m97 pattern) ----------------
// EPI 0: outb = bf16(acc*scale)           (QKV projection, pre-scaled by SCALE)
// EPI 1: exp + quadrant bf16 store + rowsum atomics   (scores)
// EPI 2: outb = bf16(acc / rs[row])       (PV, normalized)
// EPI 3: outf = acc                       (final projection, fp32 out)

template <int EPI>
__global__ __launch_bounds__(256)
void gemm_bt(const u16* __restrict__ A, const u16* __restrict__ B,
             int lda, int ldb, int K, int ldc,
             u16* __restrict__ outb, float* __restrict__ outf,
             float scale, const float* __restrict__ rs,
             u16* __restrict__ Pcq, u16* __restrict__ Pqc,
             float* __restrict__ rowsum) {
  __shared__ __align__(16) u16 sA[128 * 64];
  __shared__ __align__(16) u16 sB[128 * 64];
  const int tid = threadIdx.x;
  const int lane = tid & 63;
  const int wave = tid >> 6;
  const int wr = (wave >> 1) * 64;
  const int wc = (wave & 1) * 64;
  const int ar = lane & 15;
  const int ak = (lane >> 4) * 8;
  const int by = blockIdx.y, bx = blockIdx.x;

  const u16* Ab = A + (size_t)(by * 128) * lda;
  const u16* Bb = B + (size_t)(bx * 128) * ldb;

  f32x4 zero = {0.0f, 0.0f, 0.0f, 0.0f};
  f32x4 acc[4][4];
#pragma unroll
  for (int i = 0; i < 4; ++i)
#pragma unroll
    for (int j = 0; j < 4; ++j) acc[i][j] = zero;

  const int sr = tid >> 3;         // 0..31
  const int sc = (tid & 7) * 8;    // 0,8,..,56

  for (int k0 = 0; k0 < K; k0 += 64) {
#pragma unroll
    for (int it = 0; it < 4; ++it) {
      int r = it * 32 + sr;
      __builtin_amdgcn_global_load_lds(
          (__attribute__((address_space(1))) void*)(Ab + (size_t)r * lda + k0 + sc),
          (__attribute__((address_space(3))) void*)(sA + r * 64 + sc), 16, 0, 0);
    }
#pragma unroll
    for (int it = 0; it < 4; ++it) {
      int r = it * 32 + sr;
      __builtin_amdgcn_global_load_lds(
          (__attribute__((address_space(1))) void*)(Bb + (size_t)r * ldb + k0 + sc),
          (__attribute__((address_space(3))) void*)(sB + r * 64 + sc), 16, 0, 0);
    }
    __syncthreads();
#pragma unroll
    for (int kk = 0; kk < 64; kk += 32) {
      bf16x8 af[4], bfr[4];
#pragma unroll
      for (int t = 0; t < 4; ++t)
        af[t] = *(const bf16x8*)(sA + (wr + t * 16 + ar) * 64 + kk + ak);
#pragma unroll
      for (int t = 0; t < 4; ++t)
        bfr[t] = *(const bf16x8*)(sB + (wc + t * 16 + ar) * 64 + kk + ak);
#pragma unroll
      for (int tm = 0; tm < 4; ++tm)
#pragma unroll
        for (int tn = 0; tn < 4; ++tn)
          acc[tm][tn] = __builtin_amdgcn_mfma_f32_16x16x32_bf16(
              af[tm], bfr[tn], acc[tm][tn], 0, 0, 0);
    }
    __syncthreads();
  }

  // Epilogue. C/D layout (verified m89): row=(lane>>4)*4+reg, col=lane&15.
  const int qr = (lane >> 4) * 4;
  const int qc = lane & 15;

  if constexpr (EPI == 0) {
#pragma unroll
    for (int tm = 0; tm < 4; ++tm)
#pragma unroll
      for (int r = 0; r < 4; ++r) {
        int row = by * 128 + wr + tm * 16 + qr + r;
#pragma unroll
        for (int tn = 0; tn < 4; ++tn) {
          int col = bx * 128 + wc + tn * 16 + qc;
          outb[(size_t)row * ldc + col] = f2b(acc[tm][tn][r] * scale);
        }
      }
  } else if constexpr (EPI == 1) {
    const bool top = (by < 32);
    const bool left = (bx < 32);
    u16* pdst = nullptr;
    if (top && !left) pdst = Pcq;
    if (!top && left) pdst = Pqc;
    const int rofs = top ? 0 : 4096;
    const int cofs = left ? 0 : 4096;
#pragma unroll
    for (int tm = 0; tm < 4; ++tm) {
      float rsum[4] = {0.f, 0.f, 0.f, 0.f};
#pragma unroll
      for (int tn = 0; tn < 4; ++tn) {
        float e[4];
#pragma unroll
        for (int r = 0; r < 4; ++r) {
          e[r] = __expf(acc[tm][tn][r]);
          rsum[r] += e[r];
        }
        if (pdst) {
          int col = bx * 128 + wc + tn * 16 + qc - cofs;
#pragma unroll
          for (int r = 0; r < 4; ++r) {
            int row = by * 128 + wr + tm * 16 + qr + r - rofs;
            pdst[(size_t)row * 4096 + col] = f2b(e[r]);
          }
        }
      }
#pragma unroll
      for (int r = 0; r < 4; ++r) {
        float v = rsum[r];
        v += __shfl_xor(v, 1);
        v += __shfl_xor(v, 2);
        v += __shfl_xor(v, 4);
        v += __shfl_xor(v, 8);
        if ((lane & 15) == 0)
          atomicAdd(&rowsum[by * 128 + wr + tm * 16 + qr + r], v);
      }
    }
  } else if constexpr (EPI == 2) {
#pragma unroll
    for (int tm = 0; tm < 4; ++tm)
#pragma unroll
      for (int r = 0; r < 4; ++r) {
        int row = by * 128 + wr + tm * 16 + qr + r;
        float inv = 1.0f / rs[row];
#pragma unroll
        for (int tn = 0; tn < 4; ++tn) {
          int col = bx * 128 + wc + tn * 16 + qc;
          outb[(size_t)row * ldc + col] = f2b(acc[tm][tn][r] * inv);
        }
      }
  } else {
#pragma unroll
    for (int tm = 0; tm < 4; ++tm)
#pragma unroll
      for (int r = 0; r < 4; ++r) {
        int row = by * 128 + wr + tm * 16 + qr + r;
#pragma unroll
        for (int tn = 0; tn < 4; ++tn) {
          int col = bx * 128 + wc + tn * 16 + qc;
          outf[(size_t)row * ldc + col] = acc[tm][tn][r];
        }
      }
  }
}

// ---------------- launcher ----------------

extern "C" void kernel_launch(void* const* d_in, const int* in_sizes, int n_in,
                              void* d_out, int out_size, void* d_ws, size_t ws_size,
                              hipStream_t stream) {
  (void)in_sizes; (void)n_in; (void)out_size; (void)ws_size;
  const float* query = (const float*)d_in[0];
  const float* s     = (const float*)d_in[1];
  const float* tg    = (const float*)d_in[2];
  const float* Wqkv  = (const float*)d_in[3];
  const float* Wps   = (const float*)d_in[4];
  const float* Wpq   = (const float*)d_in[5];
  float* out = (float*)d_out;

  char* ws = (char*)d_ws;
  u16* cB     = (u16*)ws; ws += (size_t)8192 * 1024 * 2;
  u16* qks    = (u16*)ws; ws += (size_t)8192 * 2048 * 2;
  u16* queryT = (u16*)ws; ws += (size_t)1024 * 4096 * 2;
  u16* sT     = (u16*)ws; ws += (size_t)1024 * 4096 * 2;
  u16* WqkB   = (u16*)ws; ws += (size_t)2048 * 1024 * 2;
  u16* WpsB   = (u16*)ws; ws += (size_t)1024 * 1024 * 2;
  u16* WpqB   = (u16*)ws; ws += (size_t)1024 * 1024 * 2;
  u16* Pcq    = (u16*)ws; ws += (size_t)4096 * 4096 * 2;
  u16* Pqc    = (u16*)ws; ws += (size_t)4096 * 4096 * 2;
  u16* Ys     = (u16*)ws; ws += (size_t)4096 * 1024 * 2;
  u16* Yq     = (u16*)ws; ws += (size_t)4096 * 1024 * 2;
  float* rowsum = (float*)ws;  // 8192 floats

  const float SCALE = 0.17677669529663687f;  // 1024^-0.25

  hipMemsetAsync(rowsum, 0, 8192 * sizeof(float), stream);
  prep_c<<<4096, 256, 0, stream>>>(query, s, tg, cB);
  conv_bf16<<<1024, 256, 0, stream>>>(Wqkv, WqkB);   // first 2048 rows (q,k); v unused
  conv_bf16<<<512, 256, 0, stream>>>(Wps, WpsB);
  conv_bf16<<<512, 256, 0, stream>>>(Wpq, WpqB);
  transpose_bf16<<<dim3(32, 128), dim3(32, 8), 0, stream>>>(query, queryT, 4096, 1024);
  transpose_bf16<<<dim3(32, 128), dim3(32, 8), 0, stream>>>(s, sT, 4096, 1024);

  // GEMM1: qks[8192,2048] = cB @ WqkB^T, pre-scaled by SCALE (both q and k)
  gemm_bt<0><<<dim3(16, 64), 256, 0, stream>>>(cB, WqkB, 1024, 1024, 1024, 2048,
                                               qks, nullptr, SCALE, nullptr,
                                               nullptr, nullptr, nullptr);
  // GEMM2: scores (8192x8192) -> exp quadrants (bf16) + row sums
  gemm_bt<1><<<dim3(64, 64), 256, 0, stream>>>(qks, qks + 1024, 2048, 2048, 1024, 0,
                                               nullptr, nullptr, 0.f, nullptr,
                                               Pcq, Pqc, rowsum);
  // GEMM3: Y = (P @ V) / rowsum   (V = query / s, via pre-transposed N x K form)
  gemm_bt<2><<<dim3(8, 32), 256, 0, stream>>>(Pcq, queryT, 4096, 4096, 4096, 1024,
                                              Ys, nullptr, 0.f, rowsum,
                                              nullptr, nullptr, nullptr);
  gemm_bt<2><<<dim3(8, 32), 256, 0, stream>>>(Pqc, sT, 4096, 4096, 4096, 1024,
                                              Yq, nullptr, 0.f, rowsum + 4096,
                                              nullptr, nullptr, nullptr);
  // GEMM4: out = Y @ Wproj^T (fp32 store straight to d_out)
  gemm_bt<3><<<dim3(8, 32), 256, 0, stream>>>(Ys, WpsB, 1024, 1024, 1024, 1024,
                                              nullptr, out, 0.f, nullptr,
                                              nullptr, nullptr, nullptr);
  gemm_bt<3><<<dim3(8, 32), 256, 0, stream>>>(Yq, WpqB, 1024, 1024, 1024, 1024,
                                              nullptr, out + (size_t)4096 * 1024, 0.f, nullptr,
                                              nullptr, nullptr, nullptr);
}

// Round 3
// 485.592 us; speedup vs baseline: 1.3824x; 1.3824x over previous
//
#include <hip/hip_runtime.h>

// Attention block: x_s = softmax(qk^T)[:4096,4096:] @ query @ Wps^T
//                  x_q = softmax(qk^T)[4096:,:4096] @ s     @ Wpq^T
// bf16 MFMA (16x16x32), fp32 accumulate. Softmax without max-subtraction
// (scores bounded); exp fused into score-GEMM epilogue; rowsums via
// shfl+atomics; normalization deferred to PV epilogue.
//
// R2: XOR-swizzled LDS layout (kills 5e7 bank-conflict cycles: row stride is
// 128B = 32 banks, so unswizzled quad-groups hit 4 banks 16-way). Swizzle is
// applied on the GLOBAL source address (global_load_lds forces LDS dst =
// base + lane*16); fragment reads index granule gl^(row&7). Also z-batched PV
// and out-proj GEMM pairs (256 -> 512 blocks; 1 -> 2 blocks/CU co-residency).

typedef unsigned short u16;
typedef __bf16 bf16x8 __attribute__((ext_vector_type(8)));
typedef float f32x4 __attribute__((ext_vector_type(4)));
typedef unsigned short u16x8 __attribute__((ext_vector_type(8)));

#define DEVI static __device__ __forceinline__

DEVI u16 f2b(float f) {  // fp32 -> bf16 round-to-nearest-even
  unsigned int u = __float_as_uint(f);
  u += 0x7fffu + ((u >> 16) & 1u);
  return (u16)(u >> 16);
}

// ---------------- prep kernels ----------------

__global__ void prep_c(const float* __restrict__ query, const float* __restrict__ s,
                       const float* __restrict__ tg, u16* __restrict__ cB) {
  int base = (blockIdx.x * 256 + threadIdx.x) << 3;
  int row = base >> 10;
  u16x8 o;
  if (row < 4096) {
    float4 a0 = *(const float4*)(s + base);
    float4 a1 = *(const float4*)(s + base + 4);
    float4 b0 = *(const float4*)(tg + base);
    float4 b1 = *(const float4*)(tg + base + 4);
    o[0] = f2b(a0.x + b0.x); o[1] = f2b(a0.y + b0.y);
    o[2] = f2b(a0.z + b0.z); o[3] = f2b(a0.w + b0.w);
    o[4] = f2b(a1.x + b1.x); o[5] = f2b(a1.y + b1.y);
    o[6] = f2b(a1.z + b1.z); o[7] = f2b(a1.w + b1.w);
  } else {
    int qb = base - 4096 * 1024;
    float4 a0 = *(const float4*)(query + qb);
    float4 a1 = *(const float4*)(query + qb + 4);
    o[0] = f2b(a0.x); o[1] = f2b(a0.y); o[2] = f2b(a0.z); o[3] = f2b(a0.w);
    o[4] = f2b(a1.x); o[5] = f2b(a1.y); o[6] = f2b(a1.z); o[7] = f2b(a1.w);
  }
  *(u16x8*)(cB + base) = o;
}

__global__ void conv_bf16(const float* __restrict__ in, u16* __restrict__ out) {
  int base = (blockIdx.x * 256 + threadIdx.x) << 3;
  float4 a0 = *(const float4*)(in + base);
  float4 a1 = *(const float4*)(in + base + 4);
  u16x8 o;
  o[0] = f2b(a0.x); o[1] = f2b(a0.y); o[2] = f2b(a0.z); o[3] = f2b(a0.w);
  o[4] = f2b(a1.x); o[5] = f2b(a1.y); o[6] = f2b(a1.z); o[7] = f2b(a1.w);
  *(u16x8*)(out + base) = o;
}

__global__ void transpose_bf16(const float* __restrict__ in, u16* __restrict__ out,
                               int R, int C) {
  __shared__ float tile[32][33];
  int c0 = blockIdx.x * 32, r0 = blockIdx.y * 32;
  int tx = threadIdx.x, ty = threadIdx.y;  // blockDim (32,8)
#pragma unroll
  for (int i = 0; i < 4; ++i)
    tile[ty + i * 8][tx] = in[(size_t)(r0 + ty + i * 8) * C + c0 + tx];
  __syncthreads();
#pragma unroll
  for (int i = 0; i < 4; ++i)
    out[(size_t)(c0 + ty + i * 8) * R + r0 + tx] = f2b(tile[tx][ty + i * 8]);
}

// ---------------- GEMM: C[M,N] = A[M,K] @ B[N,K]^T ----------------
// EPI 0: outb = bf16(acc*scale)
// EPI 1: exp + quadrant bf16 store + rowsum atomics (scores)
// EPI 2: outb = bf16(acc / rs[row])   z-batched (A/A1, B/B1, outb/outb1, rs/rs1)
// EPI 3: outf = acc                   z-batched (A/A1, B/B1, outf/outf1)

template <int EPI>
__global__ __launch_bounds__(256)
void gemm_bt(const u16* __restrict__ A, const u16* __restrict__ A1,
             const u16* __restrict__ B, const u16* __restrict__ B1,
             int lda, int ldb, int K, int ldc,
             u16* __restrict__ outb, u16* __restrict__ outb1,
             float* __restrict__ outf, float* __restrict__ outf1,
             float scale, const float* __restrict__ rs, const float* __restrict__ rs1,
             u16* __restrict__ Pcq, u16* __restrict__ Pqc,
             float* __restrict__ rowsum) {
  __shared__ __align__(16) u16 sA[128 * 64];
  __shared__ __align__(16) u16 sB[128 * 64];
  const int tid = threadIdx.x;
  const int lane = tid & 63;
  const int wave = tid >> 6;
  const int wr = (wave >> 1) * 64;
  const int wc = (wave & 1) * 64;
  const int ar = lane & 15;
  const int by = blockIdx.y, bx = blockIdx.x;
  const int z = (EPI == 2 || EPI == 3) ? blockIdx.z : 0;

  const u16* Ap = (z ? A1 : A);
  const u16* Bp = (z ? B1 : B);
  const u16* Ab = Ap + (size_t)(by * 128) * lda;
  const u16* Bb = Bp + (size_t)(bx * 128) * ldb;

  f32x4 zero = {0.0f, 0.0f, 0.0f, 0.0f};
  f32x4 acc[4][4];
#pragma unroll
  for (int i = 0; i < 4; ++i)
#pragma unroll
    for (int j = 0; j < 4; ++j) acc[i][j] = zero;

  const int sr = tid >> 3;                        // 0..31 (row within 32-row group)
  const int scL = (tid & 7) << 3;                 // LDS dst col (identity: lane*16B)
  const int scG = ((tid & 7) ^ (sr & 7)) << 3;    // swizzled GLOBAL col granule

  for (int k0 = 0; k0 < K; k0 += 64) {
#pragma unroll
    for (int it = 0; it < 4; ++it) {
      int r = it * 32 + sr;
      __builtin_amdgcn_global_load_lds(
          (__attribute__((address_space(1))) void*)(Ab + (size_t)r * lda + k0 + scG),
          (__attribute__((address_space(3))) void*)(sA + r * 64 + scL), 16, 0, 0);
    }
#pragma unroll
    for (int it = 0; it < 4; ++it) {
      int r = it * 32 + sr;
      __builtin_amdgcn_global_load_lds(
          (__attribute__((address_space(1))) void*)(Bb + (size_t)r * ldb + k0 + scG),
          (__attribute__((address_space(3))) void*)(sB + r * 64 + scL), 16, 0, 0);
    }
    __syncthreads();
#pragma unroll
    for (int kk = 0; kk < 64; kk += 32) {
      // logical granule gl = kk/8 + (lane>>4); physical = gl ^ (row&7)
      const int gl = (kk >> 3) + (lane >> 4);
      bf16x8 af[4], bfr[4];
#pragma unroll
      for (int t = 0; t < 4; ++t) {
        const int row = wr + t * 16 + ar;
        af[t] = *(const bf16x8*)(sA + row * 64 + ((gl ^ (row & 7)) << 3));
      }
#pragma unroll
      for (int t = 0; t < 4; ++t) {
        const int row = wc + t * 16 + ar;
        bfr[t] = *(const bf16x8*)(sB + row * 64 + ((gl ^ (row & 7)) << 3));
      }
#pragma unroll
      for (int tm = 0; tm < 4; ++tm)
#pragma unroll
        for (int tn = 0; tn < 4; ++tn)
          acc[tm][tn] = __builtin_amdgcn_mfma_f32_16x16x32_bf16(
              af[tm], bfr[tn], acc[tm][tn], 0, 0, 0);
    }
    __syncthreads();
  }

  // Epilogue. C/D layout (m89): row=(lane>>4)*4+reg, col=lane&15.
  const int qr = (lane >> 4) * 4;
  const int qc = lane & 15;

  if constexpr (EPI == 0) {
#pragma unroll
    for (int tm = 0; tm < 4; ++tm)
#pragma unroll
      for (int r = 0; r < 4; ++r) {
        int row = by * 128 + wr + tm * 16 + qr + r;
#pragma unroll
        for (int tn = 0; tn < 4; ++tn) {
          int col = bx * 128 + wc + tn * 16 + qc;
          outb[(size_t)row * ldc + col] = f2b(acc[tm][tn][r] * scale);
        }
      }
  } else if constexpr (EPI == 1) {
    const bool top = (by < 32);
    const bool left = (bx < 32);
    u16* pdst = nullptr;
    if (top && !left) pdst = Pcq;
    if (!top && left) pdst = Pqc;
    const int rofs = top ? 0 : 4096;
    const int cofs = left ? 0 : 4096;
#pragma unroll
    for (int tm = 0; tm < 4; ++tm) {
      float rsum[4] = {0.f, 0.f, 0.f, 0.f};
#pragma unroll
      for (int tn = 0; tn < 4; ++tn) {
        float e[4];
#pragma unroll
        for (int r = 0; r < 4; ++r) {
          e[r] = __expf(acc[tm][tn][r]);
          rsum[r] += e[r];
        }
        if (pdst) {
          int col = bx * 128 + wc + tn * 16 + qc - cofs;
#pragma unroll
          for (int r = 0; r < 4; ++r) {
            int row = by * 128 + wr + tm * 16 + qr + r - rofs;
            pdst[(size_t)row * 4096 + col] = f2b(e[r]);
          }
        }
      }
#pragma unroll
      for (int r = 0; r < 4; ++r) {
        float v = rsum[r];
        v += __shfl_xor(v, 1);
        v += __shfl_xor(v, 2);
        v += __shfl_xor(v, 4);
        v += __shfl_xor(v, 8);
        if ((lane & 15) == 0)
          atomicAdd(&rowsum[by * 128 + wr + tm * 16 + qr + r], v);
      }
    }
  } else if constexpr (EPI == 2) {
    u16* ob = z ? outb1 : outb;
    const float* rsz = z ? rs1 : rs;
#pragma unroll
    for (int tm = 0; tm < 4; ++tm)
#pragma unroll
      for (int r = 0; r < 4; ++r) {
        int row = by * 128 + wr + tm * 16 + qr + r;
        float inv = 1.0f / rsz[row];
#pragma unroll
        for (int tn = 0; tn < 4; ++tn) {
          int col = bx * 128 + wc + tn * 16 + qc;
          ob[(size_t)row * ldc + col] = f2b(acc[tm][tn][r] * inv);
        }
      }
  } else {
    float* of = z ? outf1 : outf;
#pragma unroll
    for (int tm = 0; tm < 4; ++tm)
#pragma unroll
      for (int r = 0; r < 4; ++r) {
        int row = by * 128 + wr + tm * 16 + qr + r;
#pragma unroll
        for (int tn = 0; tn < 4; ++tn) {
          int col = bx * 128 + wc + tn * 16 + qc;
          of[(size_t)row * ldc + col] = acc[tm][tn][r];
        }
      }
  }
}

// ---------------- launcher ----------------

extern "C" void kernel_launch(void* const* d_in, const int* in_sizes, int n_in,
                              void* d_out, int out_size, void* d_ws, size_t ws_size,
                              hipStream_t stream) {
  (void)in_sizes; (void)n_in; (void)out_size; (void)ws_size;
  const float* query = (const float*)d_in[0];
  const float* s     = (const float*)d_in[1];
  const float* tg    = (const float*)d_in[2];
  const float* Wqkv  = (const float*)d_in[3];
  const float* Wps   = (const float*)d_in[4];
  const float* Wpq   = (const float*)d_in[5];
  float* out = (float*)d_out;

  char* ws = (char*)d_ws;
  u16* cB     = (u16*)ws; ws += (size_t)8192 * 1024 * 2;
  u16* qks    = (u16*)ws; ws += (size_t)8192 * 2048 * 2;
  u16* queryT = (u16*)ws; ws += (size_t)1024 * 4096 * 2;
  u16* sT     = (u16*)ws; ws += (size_t)1024 * 4096 * 2;
  u16* WqkB   = (u16*)ws; ws += (size_t)2048 * 1024 * 2;
  u16* WpsB   = (u16*)ws; ws += (size_t)1024 * 1024 * 2;
  u16* WpqB   = (u16*)ws; ws += (size_t)1024 * 1024 * 2;
  u16* Pcq    = (u16*)ws; ws += (size_t)4096 * 4096 * 2;
  u16* Pqc    = (u16*)ws; ws += (size_t)4096 * 4096 * 2;
  u16* Ys     = (u16*)ws; ws += (size_t)4096 * 1024 * 2;
  u16* Yq     = (u16*)ws; ws += (size_t)4096 * 1024 * 2;
  float* rowsum = (float*)ws;  // 8192 floats

  const float SCALE = 0.17677669529663687f;  // 1024^-0.25

  (void)hipMemsetAsync(rowsum, 0, 8192 * sizeof(float), stream);
  prep_c<<<4096, 256, 0, stream>>>(query, s, tg, cB);
  conv_bf16<<<1024, 256, 0, stream>>>(Wqkv, WqkB);   // q,k rows only; v unused
  conv_bf16<<<512, 256, 0, stream>>>(Wps, WpsB);
  conv_bf16<<<512, 256, 0, stream>>>(Wpq, WpqB);
  transpose_bf16<<<dim3(32, 128), dim3(32, 8), 0, stream>>>(query, queryT, 4096, 1024);
  transpose_bf16<<<dim3(32, 128), dim3(32, 8), 0, stream>>>(s, sT, 4096, 1024);

  // GEMM1: qks[8192,2048] = cB @ WqkB^T, pre-scaled by SCALE
  gemm_bt<0><<<dim3(16, 64), 256, 0, stream>>>(
      cB, nullptr, WqkB, nullptr, 1024, 1024, 1024, 2048,
      qks, nullptr, nullptr, nullptr, SCALE, nullptr, nullptr,
      nullptr, nullptr, nullptr);
  // GEMM2: scores (8192x8192) -> exp quadrants (bf16) + row sums
  gemm_bt<1><<<dim3(64, 64), 256, 0, stream>>>(
      qks, nullptr, qks + 1024, nullptr, 2048, 2048, 1024, 0,
      nullptr, nullptr, nullptr, nullptr, 0.f, nullptr, nullptr,
      Pcq, Pqc, rowsum);
  // GEMM3 (z-batched): Ys = (Pcq@query)/rs ; Yq = (Pqc@s)/rs
  gemm_bt<2><<<dim3(8, 32, 2), 256, 0, stream>>>(
      Pcq, Pqc, queryT, sT, 4096, 4096, 4096, 1024,
      Ys, Yq, nullptr, nullptr, 0.f, rowsum, rowsum + 4096,
      nullptr, nullptr, nullptr);
  // GEMM4 (z-batched): out = [Ys@Wps^T ; Yq@Wpq^T] (fp32)
  gemm_bt<3><<<dim3(8, 32, 2), 256, 0, stream>>>(
      Ys, Yq, WpsB, WpqB, 1024, 1024, 1024, 1024,
      nullptr, nullptr, out, out + (size_t)4096 * 1024, 0.f, nullptr, nullptr,
      nullptr, nullptr, nullptr);
}